// Round 4
// baseline (341.342 us; speedup 1.0000x reference)
//
#include <hip/hip_runtime.h>
#include <math.h>

#define NTOK (16 * 8192)   // 131072 tokens
#define H    256
#define E    32
#define SEQ  8192
#define BSZ  16

// Named-scalar accumulators (rounds 0/1: array alloca -> scratch, 556MB HBM
// writes). Round 2 (64 named accs + LDS w): no scratch writes but VGPR=56 =>
// accs were NOT register-resident (AGPR shuffling / per-expert re-reads,
// ~33TB/s of L2 traffic, 121us). Round 3/4: 32 accs only + w via SGPR.
#define FOR_E(M) M(0) M(1) M(2) M(3) M(4) M(5) M(6) M(7) \
                 M(8) M(9) M(10) M(11) M(12) M(13) M(14) M(15) \
                 M(16) M(17) M(18) M(19) M(20) M(21) M(22) M(23) \
                 M(24) M(25) M(26) M(27) M(28) M(29) M(30) M(31)

__device__ __forceinline__ float waveReduceSum(float v) {
#pragma unroll
    for (int off = 32; off > 0; off >>= 1) v += __shfl_xor(v, off, 64);
    return v;
}

// ---------------- zero the workspace accumulators ----------------
__global__ __launch_bounds__(256) void zero_ws_kernel(float* ws) {
    int i = blockIdx.x * 256 + threadIdx.x;
    if (i < BSZ * E * 2) ws[i] = 0.0f;
}

// ---------------- main gate kernel ----------------
// 1 token per thread, full 256-h row. w is read at wave-uniform addresses
// (literal e, uniform hc) -> compiler emits s_load; w values are SGPR operands
// to v_fmac (1 SGPR src allowed). NO LDS for w: removes the 2M broadcast
// ds_read_b128 (~27us min) and the 32KB/block occupancy coupling.
// 32 named accs + 6 float4 prefetch ~= 70 VGPR: guaranteed register-resident.
// Epilogue is fully lane-local (each lane owns its token's 32 logits).
__global__ __launch_bounds__(256, 2) void gate_kernel(
    const float* __restrict__ x, const float* __restrict__ w,
    float* __restrict__ out, float* __restrict__ ws_cnt, float* __restrict__ ws_sum)
{
    __shared__ float s_sum[E];   // per-block aux aggregation (cuts global
    __shared__ float s_cnt[E];   // atomics 131K -> 32K: kills serialized tail)

    const int tid   = threadIdx.x;
    const int lane  = tid & 63;
    const int token = blockIdx.x * 256 + tid;
    const float* xb = x + (size_t)token * H;

    if (tid < E) { s_sum[tid] = 0.0f; s_cnt[tid] = 0.0f; }
    __syncthreads();

#define DECL_ACC(e) float a##e = 0.0f;
    FOR_E(DECL_ACC)

    // ---- 2-iteration-deep x prefetch: 4-6 float4 in flight covers ~900cy
    // HBM latency against a ~512cy/iter VALU body with 2 waves/SIMD.
    float4 c0 = *(const float4*)(xb);
    float4 c1 = *(const float4*)(xb + 4);
    float4 d0 = *(const float4*)(xb + 8);
    float4 d1 = *(const float4*)(xb + 12);

#pragma unroll 1
    for (int hc = 0; hc < H; hc += 8) {
        const int hn = (hc + 16) & (H - 1);   // wraps on last 2 iters (L1-hot, unused)
        const float4 e0 = *(const float4*)(xb + hn);
        const float4 e1 = *(const float4*)(xb + hn + 4);

        // Per expert: 2 uniform (SGPR) w loads feed 8 v_fmac into a register acc.
#define FMA_E(e) { \
        const float4 w0 = *(const float4*)(w + (e) * H + hc); \
        const float4 w1 = *(const float4*)(w + (e) * H + hc + 4); \
        float t = a##e; \
        t = fmaf(w0.x, c0.x, t); t = fmaf(w0.y, c0.y, t); \
        t = fmaf(w0.z, c0.z, t); t = fmaf(w0.w, c0.w, t); \
        t = fmaf(w1.x, c1.x, t); t = fmaf(w1.y, c1.y, t); \
        t = fmaf(w1.z, c1.z, t); t = fmaf(w1.w, c1.w, t); \
        a##e = t; }
        FOR_E(FMA_E)

        c0 = d0; c1 = d1; d0 = e0; d1 = e1;
    }

    // ---- lane-local finalize: argmax (strict > = earliest index on ties,
    // matches top_k), softmax score at argmax = 1/sum(exp(L-m)).
    float m  = -3.402823466e+38f;
    int   id = 0;
#define AMAX_E(e) if (a##e > m) { m = a##e; id = (e); }
    FOR_E(AMAX_E)

    float ss = 0.0f;
#define EXP_E(e) const float p##e = __expf(a##e - m); ss += p##e;
    FOR_E(EXP_E)

    const float inv = 1.0f / ss;       // SCALING = 1.0
    out[token]        = (float)id;
    out[NTOK + token] = inv;

    // ---- aux-loss: wave-reduce softmax probs + argmax counts, aggregate
    // per block in LDS, then one global atomic set per block.
#define AUX_E(e) { \
        const float sc = waveReduceSum(p##e * inv); \
        const unsigned long long bl = __ballot(id == (e)); \
        if (lane == 0) { \
            atomicAdd(&s_sum[(e)], sc); \
            if (bl) atomicAdd(&s_cnt[(e)], (float)__popcll(bl)); \
        } }
    FOR_E(AUX_E)

    __syncthreads();
    if (tid < E) {
        const int b = blockIdx.x >> 5;   // 256 tokens/block, 32 blocks/batch
        atomicAdd(&ws_sum[b * E + tid], s_sum[tid]);
        const float cn = s_cnt[tid];
        if (cn != 0.0f) atomicAdd(&ws_cnt[b * E + tid], cn);
    }
}

// ---------------- aux loss reduction ----------------
__global__ __launch_bounds__(256) void aux_kernel(
    const float* __restrict__ ws_cnt, const float* __restrict__ ws_sum,
    float* __restrict__ out)
{
    const int tid = threadIdx.x;
    float p = 0.0f;
    for (int i = tid; i < BSZ * E; i += 256)
        p += ws_cnt[i] * ws_sum[i];

    __shared__ float red[4];
#pragma unroll
    for (int off = 32; off > 0; off >>= 1)
        p += __shfl_xor(p, off, 64);
    if ((tid & 63) == 0) red[tid >> 6] = p;
    __syncthreads();
    if (tid == 0) {
        float t = red[0] + red[1] + red[2] + red[3];
        // aux = sum_be cnt*ssum * alpha / (B * (SEQ/E) * SEQ)
        out[2 * NTOK] = t * (0.001f / (16.0f * 256.0f * 8192.0f));
    }
}

extern "C" void kernel_launch(void* const* d_in, const int* in_sizes, int n_in,
                              void* d_out, int out_size, void* d_ws, size_t ws_size,
                              hipStream_t stream) {
    const float* x = (const float*)d_in[0];
    const float* w = (const float*)d_in[1];
    float* out    = (float*)d_out;
    float* ws     = (float*)d_ws;
    float* ws_cnt = ws;
    float* ws_sum = ws + BSZ * E;

    zero_ws_kernel<<<4, 256, 0, stream>>>(ws);
    gate_kernel<<<NTOK / 256, 256, 0, stream>>>(x, w, out, ws_cnt, ws_sum);
    aux_kernel<<<1, 256, 0, stream>>>(ws_cnt, ws_sum, out);
}

// Round 5
// 307.208 us; speedup vs baseline: 1.1111x; 1.1111x over previous
//
#include <hip/hip_runtime.h>
#include <math.h>

#define NTOK (16 * 8192)   // 131072 tokens
#define H    256
#define E    32
#define SEQ  8192
#define BSZ  16
#define LPAD 33            // logit row pad: stride 33 dwords -> conflict-free

// History: r0/r1 array accs -> scratch (556MB writes). r2 (64 named accs, LDS w):
// VGPR=56, accs demoted, 121us. r4 (32 named accs, SGPR w): VGPR=36, accs
// demoted again (scheduler hoists 64 w-loads -> 256-reg spike -> allocator
// demotes long-lived accs to AGPR copies; VALU 4x inflated). r5: expert-group
// tiling, 8 accs live max -- demotion structurally impossible. Logits parked
// in private LDS rows (no barrier needed: each thread owns its row).

__device__ __forceinline__ float waveReduceSum(float v) {
#pragma unroll
    for (int off = 32; off > 0; off >>= 1) v += __shfl_xor(v, off, 64);
    return v;
}

// ---------------- zero the workspace accumulators ----------------
__global__ __launch_bounds__(256) void zero_ws_kernel(float* ws) {
    int i = blockIdx.x * 256 + threadIdx.x;
    if (i < BSZ * E * 2) ws[i] = 0.0f;
}

// 8 fmacs for expert G*8+K into named scalar ACC (w addr wave-uniform -> s_load)
#define FMA8(G, K, ACC) { \
    const float4 w0 = *(const float4*)(w + ((G) * 8 + (K)) * H + hc);     \
    const float4 w1 = *(const float4*)(w + ((G) * 8 + (K)) * H + hc + 4); \
    ACC = fmaf(w0.x, c0.x, ACC); ACC = fmaf(w0.y, c0.y, ACC); \
    ACC = fmaf(w0.z, c0.z, ACC); ACC = fmaf(w0.w, c0.w, ACC); \
    ACC = fmaf(w1.x, c1.x, ACC); ACC = fmaf(w1.y, c1.y, ACC); \
    ACC = fmaf(w1.z, c1.z, ACC); ACC = fmaf(w1.w, c1.w, ACC); }

// One expert-group pass: 8 named accs, full-H loop, 2-deep x prefetch,
// park 8 logits in this thread's private LDS row.
#define GEMM_GROUP(G) { \
    float b0 = 0.f, b1 = 0.f, b2 = 0.f, b3 = 0.f, \
          b4 = 0.f, b5 = 0.f, b6 = 0.f, b7 = 0.f; \
    float4 c0 = *(const float4*)(xb); \
    float4 c1 = *(const float4*)(xb + 4); \
    float4 d0 = *(const float4*)(xb + 8); \
    float4 d1 = *(const float4*)(xb + 12); \
    _Pragma("unroll 1") \
    for (int hc = 0; hc < H; hc += 8) { \
        const int hn = (hc + 16) & (H - 1);   /* wraps on last 2 iters (unused) */ \
        const float4 e0 = *(const float4*)(xb + hn); \
        const float4 e1 = *(const float4*)(xb + hn + 4); \
        FMA8(G, 0, b0) FMA8(G, 1, b1) FMA8(G, 2, b2) FMA8(G, 3, b3) \
        FMA8(G, 4, b4) FMA8(G, 5, b5) FMA8(G, 6, b6) FMA8(G, 7, b7) \
        c0 = d0; c1 = d1; d0 = e0; d1 = e1; \
    } \
    float* lr = lrow + (G) * 8; \
    lr[0] = b0; lr[1] = b1; lr[2] = b2; lr[3] = b3; \
    lr[4] = b4; lr[5] = b5; lr[6] = b6; lr[7] = b7; }

// ---------------- main gate kernel ----------------
__global__ __launch_bounds__(256, 2) void gate_kernel(
    const float* __restrict__ x, const float* __restrict__ w,
    float* __restrict__ out, float* __restrict__ ws_cnt, float* __restrict__ ws_sum)
{
    __shared__ float logit_lds[256 * LPAD];   // 33KB: [tid][e], private rows
    __shared__ float s_sum[E];                // per-block aux aggregation
    __shared__ float s_cnt[E];

    const int tid   = threadIdx.x;
    const int lane  = tid & 63;
    const int token = blockIdx.x * 256 + tid;
    const float* xb = x + (size_t)token * H;
    float* lrow     = logit_lds + tid * LPAD;

    if (tid < E) { s_sum[tid] = 0.0f; s_cnt[tid] = 0.0f; }
    __syncthreads();

    // ---- 4 expert-group passes (x re-reads are L3-resident: FETCH_SIZE=67MB
    // < 134MB input in r4 proves Infinity Cache holds x) ----
    GEMM_GROUP(0)
    GEMM_GROUP(1)
    GEMM_GROUP(2)
    GEMM_GROUP(3)

    // ---- pass 1: max + argmax over my 32 logits (strict > = earliest index
    // on ties, matches top_k) ----
    float m  = -3.402823466e+38f;
    int   id = 0;
#pragma unroll
    for (int e = 0; e < E; ++e) {
        const float v = lrow[e];
        if (v > m) { m = v; id = e; }
    }

    // ---- pass 2: exp, store p back to LDS (avoids recomputing exp in aux),
    // sum -> softmax score at argmax = 1/sum ----
    float ss = 0.0f;
#pragma unroll
    for (int e = 0; e < E; ++e) {
        const float p = __expf(lrow[e] - m);
        lrow[e] = p;
        ss += p;
    }
    const float inv = 1.0f / ss;       // SCALING = 1.0
    out[token]        = (float)id;
    out[NTOK + token] = inv;

    // ---- pass 3: aux-loss, streamed per expert (no 32-reg live set):
    // wave-reduce probs + ballot counts, aggregate per block in LDS ----
#pragma unroll
    for (int e = 0; e < E; ++e) {
        const float sc = waveReduceSum(lrow[e] * inv);
        const unsigned long long bl = __ballot(id == e);
        if (lane == 0) {
            atomicAdd(&s_sum[e], sc);
            if (bl) atomicAdd(&s_cnt[e], (float)__popcll(bl));
        }
    }

    __syncthreads();
    if (tid < E) {
        const int b = blockIdx.x >> 5;   // 256 tokens/block, 32 blocks/batch
        atomicAdd(&ws_sum[b * E + tid], s_sum[tid]);
        const float cn = s_cnt[tid];
        if (cn != 0.0f) atomicAdd(&ws_cnt[b * E + tid], cn);
    }
}

// ---------------- aux loss reduction ----------------
__global__ __launch_bounds__(256) void aux_kernel(
    const float* __restrict__ ws_cnt, const float* __restrict__ ws_sum,
    float* __restrict__ out)
{
    const int tid = threadIdx.x;
    float p = 0.0f;
    for (int i = tid; i < BSZ * E; i += 256)
        p += ws_cnt[i] * ws_sum[i];

    __shared__ float red[4];
#pragma unroll
    for (int off = 32; off > 0; off >>= 1)
        p += __shfl_xor(p, off, 64);
    if ((tid & 63) == 0) red[tid >> 6] = p;
    __syncthreads();
    if (tid == 0) {
        float t = red[0] + red[1] + red[2] + red[3];
        // aux = sum_be cnt*ssum * alpha / (B * (SEQ/E) * SEQ)
        out[2 * NTOK] = t * (0.001f / (16.0f * 256.0f * 8192.0f));
    }
}

extern "C" void kernel_launch(void* const* d_in, const int* in_sizes, int n_in,
                              void* d_out, int out_size, void* d_ws, size_t ws_size,
                              hipStream_t stream) {
    const float* x = (const float*)d_in[0];
    const float* w = (const float*)d_in[1];
    float* out    = (float*)d_out;
    float* ws     = (float*)d_ws;
    float* ws_cnt = ws;
    float* ws_sum = ws + BSZ * E;

    zero_ws_kernel<<<4, 256, 0, stream>>>(ws);
    gate_kernel<<<NTOK / 256, 256, 0, stream>>>(x, w, out, ws_cnt, ws_sum);
    aux_kernel<<<1, 256, 0, stream>>>(ws_cnt, ws_sum, out);
}